// Round 1
// baseline (16547.696 us; speedup 1.0000x reference)
//
#include <hip/hip_runtime.h>

// Critic_Net pointer-network forward. All fp32 (no fp32 MFMA on CDNA4).
// Structure:
//   k_prep_ec    : fold embedding into encoder input coeffs C = Wih @ W_embed  [2][512][4]
//   k_prep_tr    : transpose/concat weights for coalesced k-loops
//   k_encoder    : persistent bidir LSTM, batch-parallel (8 rows/block), T-loop inside
//   k_refgemm    : ref = enc @ W_ref.T, written transposed as refT[B][D][T]
//   k_process    : persistent 100-step pointer loop (2 cells + attention + glimpse)
//   k_mlp        : final 2-layer head -> d_out[512]

constexpr int kH = 128, kE = 128, kD = 256, kB = 512, kT = 100, kG = 512, kMID = 100;

// ws layout (float offsets)
constexpr size_t WS_ENC   = 0;                               // [B][T][D]
constexpr size_t WS_REFT  = WS_ENC   + (size_t)kB * kT * kD; // [B][D][T]
constexpr size_t WS_EWHHT = WS_REFT  + (size_t)kB * kD * kT; // [2][H][G]
constexpr size_t WS_ECG   = WS_EWHHT + (size_t)2 * kH * kG;  // [2][G][4] {c0,c1,bias,pad}
constexpr size_t WS_PWIHT = WS_ECG   + (size_t)2 * kG * 4;   // [D][1024]  (f|b concat)
constexpr size_t WS_PWHHT = WS_PWIHT + (size_t)kD * 1024;    // [H][1024]
constexpr size_t WS_PB    = WS_PWHHT + (size_t)kH * 1024;    // [1024]
constexpr size_t WS_WQT   = WS_PB    + 1024;                 // [D][D]
constexpr size_t WS_WREFT = WS_WQT   + (size_t)kD * kD;      // [D][D]
constexpr size_t WS_HST   = WS_WREFT + (size_t)kD * kD;      // [4][B][H] hf,cf,hb,cb
constexpr size_t WS_POUT  = WS_HST   + (size_t)4 * kB * kH;  // [B][D]

__device__ __forceinline__ float rcpf(float x) { return __builtin_amdgcn_rcpf(x); }
__device__ __forceinline__ float sigf(float x) { return rcpf(1.0f + __expf(-x)); }
__device__ __forceinline__ float tanhf_(float x) {
    float t = __expf(-2.0f * fabsf(x));
    float r = (1.0f - t) * rcpf(1.0f + t);
    return copysignf(r, x);
}

// ---------------- prep: encoder input coefficients ----------------
__global__ void k_prep_ec(const float* __restrict__ Wih_f, const float* __restrict__ Wih_b,
                          const float* __restrict__ b_f, const float* __restrict__ b_b,
                          const float* __restrict__ Wemb, float* __restrict__ ws) {
    int id = blockIdx.x * 256 + threadIdx.x;   // 0..1023 : (dir, j)
    int dir = id >> 9, j = id & 511;
    const float* Wih = dir ? Wih_b : Wih_f;
    const float* bb  = dir ? b_b   : b_f;
    float c0 = 0.f, c1 = 0.f;
    for (int e = 0; e < kE; ++e) {
        float w = Wih[j * kE + e];
        c0 += w * Wemb[e * 2 + 0];
        c1 += w * Wemb[e * 2 + 1];
    }
    float* ecg = ws + WS_ECG + (size_t)id * 4;
    ecg[0] = c0; ecg[1] = c1; ecg[2] = bb[j]; ecg[3] = 0.f;
}

// ---------------- prep: weight transposes ----------------
__global__ void k_prep_tr(const float* __restrict__ eWhh_f, const float* __restrict__ eWhh_b,
                          const float* __restrict__ pWih_f, const float* __restrict__ pWih_b,
                          const float* __restrict__ pWhh_f, const float* __restrict__ pWhh_b,
                          const float* __restrict__ pb_f, const float* __restrict__ pb_b,
                          const float* __restrict__ Wq, const float* __restrict__ Wref,
                          float* __restrict__ ws) {
    int id = blockIdx.x * 256 + threadIdx.x;   // exactly 656,384 threads
    if (id < 131072) {                         // EWhhT [2][128][512]
        int dir = id >> 16, rem = id & 65535, k = rem >> 9, j = rem & 511;
        const float* W = dir ? eWhh_b : eWhh_f;
        ws[WS_EWHHT + id] = W[j * kH + k];
        return;
    }
    id -= 131072;
    if (id < 262144) {                         // PWihT [256][1024]
        int k = id >> 10, jc = id & 1023;
        ws[WS_PWIHT + id] = (jc < 512) ? pWih_f[jc * kD + k] : pWih_b[(jc - 512) * kD + k];
        return;
    }
    id -= 262144;
    if (id < 131072) {                         // PWhhT [128][1024]
        int k = id >> 10, jc = id & 1023;
        ws[WS_PWHHT + id] = (jc < 512) ? pWhh_f[jc * kH + k] : pWhh_b[(jc - 512) * kH + k];
        return;
    }
    id -= 131072;
    if (id < 1024) {                           // PB [1024]
        ws[WS_PB + id] = (id < 512) ? pb_f[id] : pb_b[id - 512];
        return;
    }
    id -= 1024;
    if (id < 65536) {                          // WqT [256][256]
        int k = id >> 8, n = id & 255;
        ws[WS_WQT + id] = Wq[n * kD + k];
        return;
    }
    id -= 65536;
    if (id < 65536) {                          // WrefT [256][256]
        int k = id >> 8, n = id & 255;
        ws[WS_WREFT + id] = Wref[n * kD + k];
        return;
    }
}

// ---------------- encoder: bidir LSTM, 8 rows per block ----------------
__global__ __launch_bounds__(1024) void k_encoder(const float* __restrict__ inp,
                                                  float* __restrict__ ws) {
    const int dir = blockIdx.x & 1;
    const int b0  = (blockIdx.x >> 1) * 8;
    const int tid = threadIdx.x;
    __shared__ float sh[8][kH], scs[8][kH], sg[8][kG], sx[8][2];
    { int r = tid >> 7, k = tid & 127; sh[r][k] = 0.f; scs[r][k] = 0.f; }
    const float* Wt  = ws + WS_EWHHT + (size_t)dir * kH * kG;
    const float4 cg  = *reinterpret_cast<const float4*>(ws + WS_ECG + (size_t)(dir * 512 + (tid & 511)) * 4);
    float* enc = ws + WS_ENC;
    float* hst = ws + WS_HST;
    __syncthreads();
    for (int s = 0; s < kT; ++s) {
        const int t = dir ? (kT - 1 - s) : s;
        if (tid < 16) { int r = tid >> 1, c = tid & 1; sx[r][c] = inp[((size_t)(b0 + r) * kT + t) * 2 + c]; }
        __syncthreads();
        {   // gates: thread -> column j, 4 rows (rh selects row half)
            const int j = tid & 511, rh = tid >> 9;
            float a[4];
            #pragma unroll
            for (int r4 = 0; r4 < 4; ++r4) {
                int R = rh * 4 + r4;
                a[r4] = cg.z + sx[R][0] * cg.x + sx[R][1] * cg.y;
            }
            #pragma unroll 4
            for (int k = 0; k < kH; ++k) {
                float w = Wt[k * kG + j];
                #pragma unroll
                for (int r4 = 0; r4 < 4; ++r4) a[r4] += sh[rh * 4 + r4][k] * w;
            }
            #pragma unroll
            for (int r4 = 0; r4 < 4; ++r4) sg[rh * 4 + r4][j] = a[r4];
        }
        __syncthreads();
        {   // cell: thread -> (row, k)
            const int r = tid >> 7, k = tid & 127;
            float gi = sg[r][k], gf = sg[r][k + 128], gg = sg[r][k + 256], go = sg[r][k + 384];
            float cc = sigf(gf) * scs[r][k] + sigf(gi) * tanhf_(gg);
            float hh = sigf(go) * tanhf_(cc);
            scs[r][k] = cc; sh[r][k] = hh;
            enc[((size_t)(b0 + r) * kT + t) * kD + dir * kH + k] = hh;
            if (s == kT - 1) {
                hst[(size_t)(dir * 2 + 0) * kB * kH + (size_t)(b0 + r) * kH + k] = hh;
                hst[(size_t)(dir * 2 + 1) * kB * kH + (size_t)(b0 + r) * kH + k] = cc;
            }
        }
        __syncthreads();
    }
}

// ---------------- ref = enc @ W_ref.T, stored transposed [B][D][T] ----------------
__global__ __launch_bounds__(256) void k_refgemm(float* __restrict__ ws) {
    const int tid = threadIdx.x;
    const int m0 = blockIdx.x * 20;            // 20 bt-rows, always within one b
    const int b = m0 / kT, t0 = m0 % kT;
    __shared__ float se[20][kD];
    __shared__ float so[20][257];              // +1 pad for transposed read
    const float* enc = ws + WS_ENC;
    const float* WrT = ws + WS_WREFT;
    float* refT = ws + WS_REFT;
    #pragma unroll
    for (int i = 0; i < 20; ++i) se[i][tid] = enc[(size_t)(m0 + i) * kD + tid];
    __syncthreads();
    float acc[20];
    #pragma unroll
    for (int r = 0; r < 20; ++r) acc[r] = 0.f;
    #pragma unroll 2
    for (int k = 0; k < kD; ++k) {
        float w = WrT[k * kD + tid];
        #pragma unroll
        for (int r = 0; r < 20; ++r) acc[r] += se[r][k] * w;
    }
    #pragma unroll
    for (int r = 0; r < 20; ++r) so[r][tid] = acc[r];
    __syncthreads();
    #pragma unroll
    for (int i = 0; i < 20; ++i) {
        int idx = i * 256 + tid;
        int d = idx / 20, tt = idx - d * 20;
        refT[(size_t)b * kD * kT + d * kT + t0 + tt] = so[tt][d];
    }
}

// ---------------- process: 100-step pointer loop, 8 rows per block ----------------
__global__ __launch_bounds__(1024) void k_process(const float* __restrict__ vw,
                                                  const float* __restrict__ vb,
                                                  float* __restrict__ ws) {
    const int tid = threadIdx.x;
    const int b0 = blockIdx.x * 8;
    __shared__ float pin[8][kD];
    __shared__ float phf[8][kH], pcf[8][kH], phb[8][kH], pcb[8][kH];
    __shared__ float u_raw[8 * 1024];          // union: gates  OR  {q, sc, at}
    float (*pg)[1024] = (float(*)[1024])u_raw;
    float (*pq)[kD]   = (float(*)[kD])u_raw;
    float (*psc)[128] = (float(*)[128])(u_raw + 8 * kD);
    float (*pat)[128] = (float(*)[128])(u_raw + 8 * kD + 8 * 128);
    const float* PWihT = ws + WS_PWIHT;
    const float* PWhhT = ws + WS_PWHHT;
    const float* PB    = ws + WS_PB;
    const float* WqT   = ws + WS_WQT;
    const float* refT  = ws + WS_REFT;
    const float* enc   = ws + WS_ENC;
    const float* hst   = ws + WS_HST;
    {   // init states from encoder finals; pin = 0
        int r = tid >> 7, k = tid & 127;
        phf[r][k] = hst[(size_t)0 * kB * kH + (size_t)(b0 + r) * kH + k];
        pcf[r][k] = hst[(size_t)1 * kB * kH + (size_t)(b0 + r) * kH + k];
        phb[r][k] = hst[(size_t)2 * kB * kH + (size_t)(b0 + r) * kH + k];
        pcb[r][k] = hst[(size_t)3 * kB * kH + (size_t)(b0 + r) * kH + k];
    }
    for (int i = tid; i < 8 * kD; i += 1024) pin[i >> 8][i & 255] = 0.f;
    const float vbias  = vb[0];
    const float bias_j = PB[tid];
    __syncthreads();

    for (int step = 0; step < kT; ++step) {
        {   // gates: thread -> concat column j (0..511 fwd, 512..1023 bwd), 8 rows
            const int j = tid;
            float a[8];
            #pragma unroll
            for (int r = 0; r < 8; ++r) a[r] = bias_j;
            #pragma unroll 2
            for (int k = 0; k < kD; ++k) {
                float w = PWihT[k * 1024 + j];
                #pragma unroll
                for (int r = 0; r < 8; ++r) a[r] += pin[r][k] * w;
            }
            const float (*hsrc)[kH] = (j < 512) ? phf : phb;
            #pragma unroll 2
            for (int k = 0; k < kH; ++k) {
                float w = PWhhT[k * 1024 + j];
                #pragma unroll
                for (int r = 0; r < 8; ++r) a[r] += hsrc[r][k] * w;
            }
            #pragma unroll
            for (int r = 0; r < 8; ++r) pg[r][j] = a[r];
        }
        __syncthreads();
        // cell: 2048 cells
        #pragma unroll
        for (int i = 0; i < 2; ++i) {
            int cell = i * 1024 + tid;
            int r = cell >> 8, dk = cell & 255, dir = dk >> 7, k = dk & 127;
            int base = dir * 512;
            float gi = pg[r][base + k],       gf = pg[r][base + k + 128];
            float gg = pg[r][base + k + 256], go = pg[r][base + k + 384];
            float* carr = dir ? &pcb[0][0] : &pcf[0][0];
            float* harr = dir ? &phb[0][0] : &phf[0][0];
            float cc = sigf(gf) * carr[r * kH + k] + sigf(gi) * tanhf_(gg);
            float hh = sigf(go) * tanhf_(cc);
            carr[r * kH + k] = cc; harr[r * kH + k] = hh;
        }
        __syncthreads();
        if (step < kT - 1) {   // last step's attention result is discarded by the scan
            // q = pout @ Wq.T
            #pragma unroll
            for (int i = 0; i < 2; ++i) {
                int id = i * 1024 + tid;
                int n = id & 255, r = id >> 8;
                float acc = 0.f;
                #pragma unroll 2
                for (int k = 0; k < kH; ++k) acc += phf[r][k] * WqT[k * kD + n];
                #pragma unroll 2
                for (int k = 0; k < kH; ++k) acc += phb[r][k] * WqT[(k + 128) * kD + n];
                pq[r][n] = acc;
            }
            __syncthreads();
            // scores: 800 tasks (r,t)
            if (tid < 800) {
                int r = tid / 100, t = tid - (tid / 100) * 100;
                const float* rrow = refT + (size_t)(b0 + r) * kD * kT + t;
                float acc = vbias;
                #pragma unroll 2
                for (int d = 0; d < kD; ++d)
                    acc += vw[d] * tanhf_(rrow[d * kT] + pq[r][d]);
                psc[r][t] = acc;
            }
            __syncthreads();
            // softmax over t: wave w -> row w
            {
                int wv = tid >> 6, l = tid & 63;
                if (wv < 8) {
                    int r = wv;
                    float s1 = psc[r][l];
                    float s2 = (l + 64 < kT) ? psc[r][l + 64] : -3.0e38f;
                    float m = fmaxf(s1, s2);
                    #pragma unroll
                    for (int off = 32; off > 0; off >>= 1) m = fmaxf(m, __shfl_xor(m, off));
                    float e1 = __expf(s1 - m);
                    float e2 = (l + 64 < kT) ? __expf(s2 - m) : 0.f;
                    float ssum = e1 + e2;
                    #pragma unroll
                    for (int off = 32; off > 0; off >>= 1) ssum += __shfl_xor(ssum, off);
                    float inv = rcpf(ssum);
                    pat[r][l] = e1 * inv;
                    pat[r][l + 64] = e2 * inv;
                }
            }
            __syncthreads();
            // glimpse: pin[r][d] = sum_t attn[t] * enc[b][t][d]
            #pragma unroll
            for (int i = 0; i < 2; ++i) {
                int id = i * 1024 + tid;
                int d = id & 255, r = id >> 8;
                const float* erow = enc + (size_t)(b0 + r) * kT * kD + d;
                float acc = 0.f;
                #pragma unroll 4
                for (int t = 0; t < kT; ++t) acc += pat[r][t] * erow[t * kD];
                pin[r][d] = acc;
            }
            __syncthreads();
        }
    }
    // write final pout = [hf | hb]
    float* pout = ws + WS_POUT;
    #pragma unroll
    for (int i = 0; i < 2; ++i) {
        int id = i * 1024 + tid;
        int d = id & 255, r = id >> 8;
        pout[(size_t)(b0 + r) * kD + d] = (d < 128) ? phf[r][d] : phb[r][d - 128];
    }
}

// ---------------- final MLP head ----------------
__global__ __launch_bounds__(128) void k_mlp(const float* __restrict__ W1, const float* __restrict__ b1,
                                             const float* __restrict__ W2, const float* __restrict__ b2,
                                             const float* __restrict__ ws, float* __restrict__ out) {
    const int tid = threadIdx.x;
    const int b0 = blockIdx.x * 4;
    __shared__ float sp[4][kD];
    __shared__ float hid[4][kMID];
    const float* pout = ws + WS_POUT;
    #pragma unroll
    for (int i = 0; i < 8; ++i) {
        int f = i * 128 + tid;
        int r = f >> 8, k = f & 255;
        sp[r][k] = pout[(size_t)(b0 + r) * kD + k];
    }
    __syncthreads();
    if (tid < kMID) {
        int m = tid;
        #pragma unroll
        for (int r = 0; r < 4; ++r) {
            float acc = b1[m];
            for (int k = 0; k < kD; ++k) acc += sp[r][k] * W1[m * kD + k];
            hid[r][m] = fmaxf(acc, 0.f);
        }
    }
    __syncthreads();
    if (tid < 4) {
        float acc = b2[0];
        for (int m = 0; m < kMID; ++m) acc += hid[tid][m] * W2[m];
        out[b0 + tid] = acc;
    }
}

extern "C" void kernel_launch(void* const* d_in, const int* in_sizes, int n_in,
                              void* d_out, int out_size, void* d_ws, size_t ws_size,
                              hipStream_t stream) {
    (void)in_sizes; (void)n_in; (void)out_size; (void)ws_size;
    const float* inp    = (const float*)d_in[0];
    const float* Wemb   = (const float*)d_in[1];
    const float* eWih_f = (const float*)d_in[2];
    const float* eWhh_f = (const float*)d_in[3];
    const float* eb_f   = (const float*)d_in[4];
    const float* eWih_b = (const float*)d_in[5];
    const float* eWhh_b = (const float*)d_in[6];
    const float* eb_b   = (const float*)d_in[7];
    const float* Wref   = (const float*)d_in[8];
    const float* Wq     = (const float*)d_in[9];
    const float* vw     = (const float*)d_in[10];
    const float* vb     = (const float*)d_in[11];
    const float* pWih_f = (const float*)d_in[12];
    const float* pWhh_f = (const float*)d_in[13];
    const float* pb_f   = (const float*)d_in[14];
    const float* pWih_b = (const float*)d_in[15];
    const float* pWhh_b = (const float*)d_in[16];
    const float* pb_b   = (const float*)d_in[17];
    const float* W1     = (const float*)d_in[18];
    const float* b1     = (const float*)d_in[19];
    const float* W2     = (const float*)d_in[20];
    const float* b2     = (const float*)d_in[21];
    float* ws  = (float*)d_ws;
    float* out = (float*)d_out;

    k_prep_ec<<<4, 256, 0, stream>>>(eWih_f, eWih_b, eb_f, eb_b, Wemb, ws);
    k_prep_tr<<<2564, 256, 0, stream>>>(eWhh_f, eWhh_b, pWih_f, pWih_b,
                                        pWhh_f, pWhh_b, pb_f, pb_b, Wq, Wref, ws);
    k_encoder<<<128, 1024, 0, stream>>>(inp, ws);
    k_refgemm<<<2560, 256, 0, stream>>>(ws);
    k_process<<<64, 1024, 0, stream>>>(vw, vb, ws);
    k_mlp<<<128, 128, 0, stream>>>(W1, b1, W2, b2, ws, out);
}

// Round 2
// 3766.915 us; speedup vs baseline: 4.3929x; 4.3929x over previous
//
#include <hip/hip_runtime.h>

// Critic_Net pointer-network forward. All fp32 (no fp32 MFMA on CDNA4).
// R2: k_process/k_encoder restructured for full-chip occupancy + float4
// weight streaming (R1 was latency-bound: VALUBusy 8.8%, Occ 11.9%).

constexpr int kH = 128, kE = 128, kD = 256, kB = 512, kT = 100, kG = 512, kMID = 100;

// ws layout (float offsets)
constexpr size_t WS_ENC   = 0;                               // [B][T][D]
constexpr size_t WS_REFT  = WS_ENC   + (size_t)kB * kT * kD; // [B][D][T]
constexpr size_t WS_EWHHT = WS_REFT  + (size_t)kB * kD * kT; // [2][H][G]
constexpr size_t WS_ECG   = WS_EWHHT + (size_t)2 * kH * kG;  // [2][G][4] {c0,c1,bias,pad}
constexpr size_t WS_PWIHT = WS_ECG   + (size_t)2 * kG * 4;   // [D][1024]  (f|b concat)
constexpr size_t WS_PWHHT = WS_PWIHT + (size_t)kD * 1024;    // [H][1024]  (contiguous -> PW[384][1024])
constexpr size_t WS_PB    = WS_PWHHT + (size_t)kH * 1024;    // [1024]
constexpr size_t WS_WQT   = WS_PB    + 1024;                 // [D][D]
constexpr size_t WS_WREFT = WS_WQT   + (size_t)kD * kD;      // [D][D]
constexpr size_t WS_HST   = WS_WREFT + (size_t)kD * kD;      // [4][B][H] hf,cf,hb,cb
constexpr size_t WS_POUT  = WS_HST   + (size_t)4 * kB * kH;  // [B][D]

__device__ __forceinline__ float rcpf(float x) { return __builtin_amdgcn_rcpf(x); }
__device__ __forceinline__ float sigf(float x) { return rcpf(1.0f + __expf(-x)); }
__device__ __forceinline__ float tanhf_(float x) {
    float t = __expf(-2.0f * fabsf(x));
    float r = (1.0f - t) * rcpf(1.0f + t);
    return copysignf(r, x);
}

// ---------------- prep: encoder input coefficients ----------------
__global__ void k_prep_ec(const float* __restrict__ Wih_f, const float* __restrict__ Wih_b,
                          const float* __restrict__ b_f, const float* __restrict__ b_b,
                          const float* __restrict__ Wemb, float* __restrict__ ws) {
    int id = blockIdx.x * 256 + threadIdx.x;   // 0..1023 : (dir, j)
    int dir = id >> 9, j = id & 511;
    const float* Wih = dir ? Wih_b : Wih_f;
    const float* bb  = dir ? b_b   : b_f;
    float c0 = 0.f, c1 = 0.f;
    for (int e = 0; e < kE; ++e) {
        float w = Wih[j * kE + e];
        c0 += w * Wemb[e * 2 + 0];
        c1 += w * Wemb[e * 2 + 1];
    }
    float* ecg = ws + WS_ECG + (size_t)id * 4;
    ecg[0] = c0; ecg[1] = c1; ecg[2] = bb[j]; ecg[3] = 0.f;
}

// ---------------- prep: weight transposes ----------------
__global__ void k_prep_tr(const float* __restrict__ eWhh_f, const float* __restrict__ eWhh_b,
                          const float* __restrict__ pWih_f, const float* __restrict__ pWih_b,
                          const float* __restrict__ pWhh_f, const float* __restrict__ pWhh_b,
                          const float* __restrict__ pb_f, const float* __restrict__ pb_b,
                          const float* __restrict__ Wq, const float* __restrict__ Wref,
                          float* __restrict__ ws) {
    int id = blockIdx.x * 256 + threadIdx.x;   // exactly 656,384 threads
    if (id < 131072) {                         // EWhhT [2][128][512]
        int dir = id >> 16, rem = id & 65535, k = rem >> 9, j = rem & 511;
        const float* W = dir ? eWhh_b : eWhh_f;
        ws[WS_EWHHT + id] = W[j * kH + k];
        return;
    }
    id -= 131072;
    if (id < 262144) {                         // PWihT [256][1024]
        int k = id >> 10, jc = id & 1023;
        ws[WS_PWIHT + id] = (jc < 512) ? pWih_f[jc * kD + k] : pWih_b[(jc - 512) * kD + k];
        return;
    }
    id -= 262144;
    if (id < 131072) {                         // PWhhT [128][1024]
        int k = id >> 10, jc = id & 1023;
        ws[WS_PWHHT + id] = (jc < 512) ? pWhh_f[jc * kH + k] : pWhh_b[(jc - 512) * kH + k];
        return;
    }
    id -= 131072;
    if (id < 1024) {                           // PB [1024]
        ws[WS_PB + id] = (id < 512) ? pb_f[id] : pb_b[id - 512];
        return;
    }
    id -= 1024;
    if (id < 65536) {                          // WqT [256][256]
        int k = id >> 8, n = id & 255;
        ws[WS_WQT + id] = Wq[n * kD + k];
        return;
    }
    id -= 65536;
    if (id < 65536) {                          // WrefT [256][256]
        int k = id >> 8, n = id & 255;
        ws[WS_WREFT + id] = Wref[n * kD + k];
        return;
    }
}

// ---------------- encoder: bidir LSTM, 4 rows per block, float4 weights ----------------
__global__ __launch_bounds__(512) void k_encoder(const float* __restrict__ inp,
                                                 float* __restrict__ ws) {
    const int dir = blockIdx.x & 1;
    const int b0  = (blockIdx.x >> 1) * 4;
    const int tid = threadIdx.x;
    const int jq  = tid & 127;                 // 4 j's: j4 = 4*jq
    const int kg  = tid >> 7;                  // 0..3, 32 k's each
    __shared__ float shT[kH][4];               // h transposed [k][r]
    __shared__ float scs[4][kH];               // c state [r][k]
    __shared__ float sg[4][kG];                // gates [r][j]
    __shared__ float uniE[4 * 4 * 512];        // partials [kg][r][j] (32KB)
    __shared__ float sx[4][2];
    if (tid < 512) { shT[tid & 127][tid >> 7] = 0.f; scs[tid >> 7][tid & 127] = 0.f; }
    const float4* Wt4 = (const float4*)(ws + WS_EWHHT + (size_t)dir * kH * kG); // [128][128]
    const float4  cg  = *(const float4*)(ws + WS_ECG + (size_t)(dir * 512 + tid) * 4); // j = tid
    float* enc = ws + WS_ENC;
    float* hst = ws + WS_HST;
    float4* uniE4 = (float4*)uniE;
    __syncthreads();
    for (int s = 0; s < kT; ++s) {
        const int t = dir ? (kT - 1 - s) : s;
        if (tid < 8) { int r = tid >> 1, c = tid & 1; sx[r][c] = inp[((size_t)(b0 + r) * kT + t) * 2 + c]; }
        {   // partial gates: thread (jq, kg): 32 k, 4 rows, 4 j
            float a0x=0,a0y=0,a0z=0,a0w=0, a1x=0,a1y=0,a1z=0,a1w=0;
            float a2x=0,a2y=0,a2z=0,a2w=0, a3x=0,a3y=0,a3z=0,a3w=0;
            #pragma unroll 8
            for (int kk = 0; kk < 32; ++kk) {
                int k = kg * 32 + kk;
                float4 w = Wt4[k * 128 + jq];
                float4 x = *(const float4*)&shT[k][0];
                a0x += x.x*w.x; a0y += x.x*w.y; a0z += x.x*w.z; a0w += x.x*w.w;
                a1x += x.y*w.x; a1y += x.y*w.y; a1z += x.y*w.z; a1w += x.y*w.w;
                a2x += x.z*w.x; a2y += x.z*w.y; a2z += x.z*w.z; a2w += x.z*w.w;
                a3x += x.w*w.x; a3y += x.w*w.y; a3z += x.w*w.z; a3w += x.w*w.w;
            }
            uniE4[(kg * 4 + 0) * 128 + jq] = make_float4(a0x,a0y,a0z,a0w);
            uniE4[(kg * 4 + 1) * 128 + jq] = make_float4(a1x,a1y,a1z,a1w);
            uniE4[(kg * 4 + 2) * 128 + jq] = make_float4(a2x,a2y,a2z,a2w);
            uniE4[(kg * 4 + 3) * 128 + jq] = make_float4(a3x,a3y,a3z,a3w);
        }
        __syncthreads();
        {   // reduce + input term: j = tid
            #pragma unroll
            for (int r = 0; r < 4; ++r) {
                float g = cg.z + sx[r][0] * cg.x + sx[r][1] * cg.y;
                #pragma unroll
                for (int g4 = 0; g4 < 4; ++g4) g += uniE[(g4 * 4 + r) * 512 + tid];
                sg[r][tid] = g;
            }
        }
        __syncthreads();
        {   // cell: tid<512 -> (r, k)
            const int r = tid >> 7, k = tid & 127;
            float gi = sg[r][k], gf = sg[r][k + 128], gg = sg[r][k + 256], go = sg[r][k + 384];
            float cc = sigf(gf) * scs[r][k] + sigf(gi) * tanhf_(gg);
            float hh = sigf(go) * tanhf_(cc);
            scs[r][k] = cc; shT[k][r] = hh;
            enc[((size_t)(b0 + r) * kT + t) * kD + dir * kH + k] = hh;
            if (s == kT - 1) {
                hst[(size_t)(dir * 2 + 0) * kB * kH + (size_t)(b0 + r) * kH + k] = hh;
                hst[(size_t)(dir * 2 + 1) * kB * kH + (size_t)(b0 + r) * kH + k] = cc;
            }
        }
        __syncthreads();
    }
}

// ---------------- ref = enc @ W_ref.T, stored transposed [B][D][T] ----------------
__global__ __launch_bounds__(256) void k_refgemm(float* __restrict__ ws) {
    const int tid = threadIdx.x;
    const int m0 = blockIdx.x * 20;            // 20 bt-rows, always within one b
    const int b = m0 / kT, t0 = m0 % kT;
    __shared__ float se[20][kD];
    __shared__ float so[20][257];              // +1 pad for transposed read
    const float* enc = ws + WS_ENC;
    const float* WrT = ws + WS_WREFT;
    float* refT = ws + WS_REFT;
    #pragma unroll
    for (int i = 0; i < 20; ++i) se[i][tid] = enc[(size_t)(m0 + i) * kD + tid];
    __syncthreads();
    float acc[20];
    #pragma unroll
    for (int r = 0; r < 20; ++r) acc[r] = 0.f;
    #pragma unroll 2
    for (int k = 0; k < kD; ++k) {
        float w = WrT[k * kD + tid];
        #pragma unroll
        for (int r = 0; r < 20; ++r) acc[r] += se[r][k] * w;
    }
    #pragma unroll
    for (int r = 0; r < 20; ++r) so[r][tid] = acc[r];
    __syncthreads();
    #pragma unroll
    for (int i = 0; i < 20; ++i) {
        int idx = i * 256 + tid;
        int d = idx / 20, tt = idx - d * 20;
        refT[(size_t)b * kD * kT + d * kT + t0 + tt] = so[tt][d];
    }
}

// ---------------- process: 100-step pointer loop, 2 rows per block ----------------
__global__ __launch_bounds__(1024) void k_process(const float* __restrict__ vw,
                                                  const float* __restrict__ vb,
                                                  float* __restrict__ ws) {
    const int tid = threadIdx.x;
    const int b0 = blockIdx.x * 2;
    // xcat2[jh][k][r]: k<256 = pin (dup across jh), k>=256 = h(dir=jh)
    __shared__ float xcat2[2][384][2];
    __shared__ float pc[2][2][kH];             // c state [dir][r][k]
    __shared__ float uni[8192];                // 32KB union: gates-part / q-part / sc-part / gl-part
    __shared__ float gates[2][1024];
    __shared__ float qv[2][kD];
    __shared__ float at[2][128];
    __shared__ float vwS[kD];
    const float* PW4base = ws + WS_PWIHT;      // PW[384][1024] (Wih rows then Whh rows)
    const float* PB   = ws + WS_PB;
    const float* WqT  = ws + WS_WQT;
    const float* refT = ws + WS_REFT;
    const float* enc  = ws + WS_ENC;
    const float* hst  = ws + WS_HST;
    // init
    if (tid < 512) {                           // states: (r, dir, k)
        int r = tid >> 8, dirk = tid & 255, dir = dirk >> 7, k = dirk & 127;
        xcat2[dir][256 + k][r] = hst[(size_t)(dir * 2 + 0) * kB * kH + (size_t)(b0 + r) * kH + k];
        pc[dir][r][k]          = hst[(size_t)(dir * 2 + 1) * kB * kH + (size_t)(b0 + r) * kH + k];
    }
    { int jh = tid >> 9, rk = tid & 511, k = rk >> 1, r = rk & 1; xcat2[jh][k][r] = 0.f; }
    if (tid < kD) vwS[tid] = vw[tid];
    const float vbias  = vb[0];
    const float bias_j = PB[tid];
    const int jq = tid & 255;                  // gates: 4 j's
    const int kg = tid >> 8;                   // gates: 0..3, 96 k's
    const int jh = (jq >= 128);
    const float4* PW4 = (const float4*)PW4base;
    float4* uni4 = (float4*)uni;
    __syncthreads();

    for (int step = 0; step < kT; ++step) {
        {   // P1 gates partial: thread (jq,kg): 96 k x 2 rows x 4 j
            float a00=0,a01=0,a02=0,a03=0, a10=0,a11=0,a12=0,a13=0;
            const float2* xk = (const float2*)&xcat2[jh][0][0];
            #pragma unroll 8
            for (int kk = 0; kk < 96; ++kk) {
                int k = kg * 96 + kk;
                float4 w = PW4[k * 256 + jq];
                float2 x = xk[k];
                a00 += x.x*w.x; a01 += x.x*w.y; a02 += x.x*w.z; a03 += x.x*w.w;
                a10 += x.y*w.x; a11 += x.y*w.y; a12 += x.y*w.z; a13 += x.y*w.w;
            }
            uni4[(kg * 2 + 0) * 256 + jq] = make_float4(a00,a01,a02,a03);
            uni4[(kg * 2 + 1) * 256 + jq] = make_float4(a10,a11,a12,a13);
        }
        __syncthreads();
        {   // P2 gates reduce: j = tid, both rows
            #pragma unroll
            for (int r = 0; r < 2; ++r) {
                float g = bias_j;
                #pragma unroll
                for (int g4 = 0; g4 < 4; ++g4) g += uni[(g4 * 2 + r) * 1024 + tid];
                gates[r][tid] = g;
            }
        }
        __syncthreads();
        if (tid < 512) {                       // P3 cells: (r, dir, k)
            int r = tid >> 8, dirk = tid & 255, dir = dirk >> 7, k = dirk & 127;
            int base = dir * 512;
            float gi = gates[r][base + k],       gf = gates[r][base + k + 128];
            float gg = gates[r][base + k + 256], go = gates[r][base + k + 384];
            float cc = sigf(gf) * pc[dir][r][k] + sigf(gi) * tanhf_(gg);
            float hh = sigf(go) * tanhf_(cc);
            pc[dir][r][k] = cc; xcat2[dir][256 + k][r] = hh;
        }
        __syncthreads();
        if (step < kT - 1) {
            {   // P4 q partial: thread (n = tid&255, kh = tid>>8): 64 k, both rows
                int n = tid & 255, kh = tid >> 8;
                int src = kh >> 1;             // 0 -> hf, 1 -> hb
                int kk0 = (kh & 1) * 64;
                float q0 = 0.f, q1 = 0.f;
                const float2* xk = (const float2*)&xcat2[src][256][0];
                #pragma unroll 8
                for (int i = 0; i < 64; ++i) {
                    int kk = kk0 + i;
                    float w = WqT[(src * 128 + kk) * kD + n];
                    float2 x = xk[kk];
                    q0 += x.x * w; q1 += x.y * w;
                }
                uni[(kh * 2 + 0) * 256 + n] = q0;
                uni[(kh * 2 + 1) * 256 + n] = q1;
            }
            __syncthreads();
            if (tid < 512) {                   // P5 q reduce
                int r = tid >> 8, n = tid & 255;
                float q = 0.f;
                #pragma unroll
                for (int kh = 0; kh < 4; ++kh) q += uni[(kh * 2 + r) * 256 + n];
                qv[r][n] = q;
            }
            __syncthreads();
            if (tid < 800) {                   // P6 scores partial: (r, dg, t), 64 d each
                int r = tid / 400, rem = tid - r * 400;
                int dg = rem / 100, t = rem - dg * 100;
                const float* rrow = refT + ((size_t)(b0 + r) * kD + dg * 64) * kT + t;
                float acc = 0.f;
                #pragma unroll 4
                for (int i = 0; i < 64; ++i) {
                    int d = dg * 64 + i;
                    acc += vwS[d] * tanhf_(rrow[i * kT] + qv[r][d]);
                }
                uni[(r * 4 + dg) * 100 + t] = acc;
            }
            __syncthreads();
            {   // P7 softmax over t: wave r (r<2)
                int wv = tid >> 6, l = tid & 63;
                if (wv < 2) {
                    int r = wv;
                    float s1 = vbias + uni[(r*4+0)*100 + l] + uni[(r*4+1)*100 + l]
                                     + uni[(r*4+2)*100 + l] + uni[(r*4+3)*100 + l];
                    float s2 = -3.0e38f;
                    if (l + 64 < kT)
                        s2 = vbias + uni[(r*4+0)*100 + l+64] + uni[(r*4+1)*100 + l+64]
                                   + uni[(r*4+2)*100 + l+64] + uni[(r*4+3)*100 + l+64];
                    float m = fmaxf(s1, s2);
                    #pragma unroll
                    for (int off = 32; off > 0; off >>= 1) m = fmaxf(m, __shfl_xor(m, off));
                    float e1 = __expf(s1 - m);
                    float e2 = (l + 64 < kT) ? __expf(s2 - m) : 0.f;
                    float ssum = e1 + e2;
                    #pragma unroll
                    for (int off = 32; off > 0; off >>= 1) ssum += __shfl_xor(ssum, off);
                    float inv = rcpf(ssum);
                    at[r][l] = e1 * inv;
                    at[r][l + 64] = e2 * inv;
                }
            }
            __syncthreads();
            {   // P8 glimpse partial: (d = tid&255, r = bit8, th = bit9): 50 t each
                int d = tid & 255, r = (tid >> 8) & 1, th = tid >> 9;
                const float* erow = enc + ((size_t)(b0 + r) * kT + th * 50) * kD + d;
                float acc = 0.f;
                #pragma unroll 5
                for (int i = 0; i < 50; ++i)
                    acc += at[r][th * 50 + i] * erow[(size_t)i * kD];
                uni[(th * 2 + r) * 256 + d] = acc;
            }
            __syncthreads();
            if (tid < 512) {                   // P9 glimpse reduce -> pin (both jh copies)
                int r = tid >> 8, d = tid & 255;
                float v = uni[(0 * 2 + r) * 256 + d] + uni[(1 * 2 + r) * 256 + d];
                xcat2[0][d][r] = v; xcat2[1][d][r] = v;
            }
            __syncthreads();
        }
    }
    // write final pout = [hf | hb]
    float* pout = ws + WS_POUT;
    if (tid < 512) {
        int r = tid >> 8, d = tid & 255;
        pout[(size_t)(b0 + r) * kD + d] = (d < 128) ? xcat2[0][256 + d][r]
                                                    : xcat2[1][256 + d - 128][r];
    }
}

// ---------------- final MLP head ----------------
__global__ __launch_bounds__(128) void k_mlp(const float* __restrict__ W1, const float* __restrict__ b1,
                                             const float* __restrict__ W2, const float* __restrict__ b2,
                                             const float* __restrict__ ws, float* __restrict__ out) {
    const int tid = threadIdx.x;
    const int b0 = blockIdx.x * 4;
    __shared__ float sp[4][kD];
    __shared__ float hid[4][kMID];
    const float* pout = ws + WS_POUT;
    #pragma unroll
    for (int i = 0; i < 8; ++i) {
        int f = i * 128 + tid;
        int r = f >> 8, k = f & 255;
        sp[r][k] = pout[(size_t)(b0 + r) * kD + k];
    }
    __syncthreads();
    if (tid < kMID) {
        int m = tid;
        #pragma unroll
        for (int r = 0; r < 4; ++r) {
            float acc = b1[m];
            for (int k = 0; k < kD; ++k) acc += sp[r][k] * W1[m * kD + k];
            hid[r][m] = fmaxf(acc, 0.f);
        }
    }
    __syncthreads();
    if (tid < 4) {
        float acc = b2[0];
        for (int m = 0; m < kMID; ++m) acc += hid[tid][m] * W2[m];
        out[b0 + tid] = acc;
    }
}

extern "C" void kernel_launch(void* const* d_in, const int* in_sizes, int n_in,
                              void* d_out, int out_size, void* d_ws, size_t ws_size,
                              hipStream_t stream) {
    (void)in_sizes; (void)n_in; (void)out_size; (void)ws_size;
    const float* inp    = (const float*)d_in[0];
    const float* Wemb   = (const float*)d_in[1];
    const float* eWih_f = (const float*)d_in[2];
    const float* eWhh_f = (const float*)d_in[3];
    const float* eb_f   = (const float*)d_in[4];
    const float* eWih_b = (const float*)d_in[5];
    const float* eWhh_b = (const float*)d_in[6];
    const float* eb_b   = (const float*)d_in[7];
    const float* Wref   = (const float*)d_in[8];
    const float* Wq     = (const float*)d_in[9];
    const float* vw     = (const float*)d_in[10];
    const float* vb     = (const float*)d_in[11];
    const float* pWih_f = (const float*)d_in[12];
    const float* pWhh_f = (const float*)d_in[13];
    const float* pb_f   = (const float*)d_in[14];
    const float* pWih_b = (const float*)d_in[15];
    const float* pWhh_b = (const float*)d_in[16];
    const float* pb_b   = (const float*)d_in[17];
    const float* W1     = (const float*)d_in[18];
    const float* b1     = (const float*)d_in[19];
    const float* W2     = (const float*)d_in[20];
    const float* b2     = (const float*)d_in[21];
    float* ws  = (float*)d_ws;
    float* out = (float*)d_out;

    k_prep_ec<<<4, 256, 0, stream>>>(eWih_f, eWih_b, eb_f, eb_b, Wemb, ws);
    k_prep_tr<<<2564, 256, 0, stream>>>(eWhh_f, eWhh_b, pWih_f, pWih_b,
                                        pWhh_f, pWhh_b, pb_f, pb_b, Wq, Wref, ws);
    k_encoder<<<256, 512, 0, stream>>>(inp, ws);
    k_refgemm<<<2560, 256, 0, stream>>>(ws);
    k_process<<<256, 1024, 0, stream>>>(vw, vb, ws);
    k_mlp<<<128, 128, 0, stream>>>(W1, b1, W2, b2, ws, out);
}

// Round 3
// 3305.220 us; speedup vs baseline: 5.0065x; 1.1397x over previous
//
#include <hip/hip_runtime.h>
#include <hip/hip_fp16.h>

// Critic_Net pointer-network forward. fp32 activations, fp16 weights (R3).
// R2 was mixed L2-BW / L3-latency bound (VALU 37%); fp16 weights halve the
// dominant per-step weight stream and its load count.

constexpr int kH = 128, kE = 128, kD = 256, kB = 512, kT = 100, kG = 512, kMID = 100;

// ws layout (float offsets)
constexpr size_t WS_ENC   = 0;                                // [B][T][D] fp32
constexpr size_t WS_REFT  = WS_ENC   + (size_t)kB * kT * kD;  // [B][D][T] fp32
constexpr size_t WS_EWHHH = WS_REFT  + (size_t)kB * kD * kT;  // half[2][128][512] (65,536 f)
constexpr size_t WS_ECG   = WS_EWHHH + 65536;                 // [2][512][4] fp32
constexpr size_t WS_PWH   = WS_ECG   + 4096;                  // half[384][1024] (196,608 f)
constexpr size_t WS_PB    = WS_PWH   + 196608;                // [1024] fp32
constexpr size_t WS_WQH   = WS_PB    + 1024;                  // half2[128][256] (32,768 f)
constexpr size_t WS_WREFT = WS_WQH   + 32768;                 // [D][D] fp32
constexpr size_t WS_HST   = WS_WREFT + (size_t)kD * kD;       // [4][B][H] fp32
constexpr size_t WS_POUT  = WS_HST   + (size_t)4 * kB * kH;   // [B][D] fp32

__device__ __forceinline__ float rcpf(float x) { return __builtin_amdgcn_rcpf(x); }
__device__ __forceinline__ float sigf(float x) { return rcpf(1.0f + __expf(-x)); }
__device__ __forceinline__ float tanhf_(float x) {
    float t = __expf(-2.0f * fabsf(x));
    float r = (1.0f - t) * rcpf(1.0f + t);
    return copysignf(r, x);
}

// ---------------- prep: encoder input coefficients ----------------
__global__ void k_prep_ec(const float* __restrict__ Wih_f, const float* __restrict__ Wih_b,
                          const float* __restrict__ b_f, const float* __restrict__ b_b,
                          const float* __restrict__ Wemb, float* __restrict__ ws) {
    int id = blockIdx.x * 256 + threadIdx.x;   // 0..1023 : (dir, j)
    int dir = id >> 9, j = id & 511;
    const float* Wih = dir ? Wih_b : Wih_f;
    const float* bb  = dir ? b_b   : b_f;
    float c0 = 0.f, c1 = 0.f;
    for (int e = 0; e < kE; ++e) {
        float w = Wih[j * kE + e];
        c0 += w * Wemb[e * 2 + 0];
        c1 += w * Wemb[e * 2 + 1];
    }
    float* ecg = ws + WS_ECG + (size_t)id * 4;
    ecg[0] = c0; ecg[1] = c1; ecg[2] = bb[j]; ecg[3] = 0.f;
}

// ---------------- prep: weight transposes (fp16 conversion) ----------------
__global__ void k_prep_tr(const float* __restrict__ eWhh_f, const float* __restrict__ eWhh_b,
                          const float* __restrict__ pWih_f, const float* __restrict__ pWih_b,
                          const float* __restrict__ pWhh_f, const float* __restrict__ pWhh_b,
                          const float* __restrict__ pb_f, const float* __restrict__ pb_b,
                          const float* __restrict__ Wq, const float* __restrict__ Wref,
                          float* __restrict__ ws) {
    int id = blockIdx.x * 256 + threadIdx.x;   // exactly 623,616 threads
    if (id < 131072) {                         // EWhhH half[2][128][512] k-major
        int dir = id >> 16, rem = id & 65535, k = rem >> 9, j = rem & 511;
        const float* W = dir ? eWhh_b : eWhh_f;
        ((__half*)(ws + WS_EWHHH))[id] = __float2half(W[j * kH + k]);
        return;
    }
    id -= 131072;
    if (id < 393216) {                         // PWh half[384][1024] k-major (Wih rows then Whh)
        int k = id >> 10, jc = id & 1023;
        float v;
        if (k < 256) v = (jc < 512) ? pWih_f[jc * kD + k]        : pWih_b[(jc - 512) * kD + k];
        else         v = (jc < 512) ? pWhh_f[jc * kH + (k - 256)] : pWhh_b[(jc - 512) * kH + (k - 256)];
        ((__half*)(ws + WS_PWH))[id] = __float2half(v);
        return;
    }
    id -= 393216;
    if (id < 1024) {                           // PB [1024] fp32
        ws[WS_PB + id] = (id < 512) ? pb_f[id] : pb_b[id - 512];
        return;
    }
    id -= 1024;
    if (id < 32768) {                          // WqP half2[128][256]: {Wq[n][2kp], Wq[n][2kp+1]}
        int kp = id >> 8, n = id & 255;
        ((__half2*)(ws + WS_WQH))[kp * 256 + n] =
            __halves2half2(__float2half(Wq[n * kD + 2 * kp]),
                           __float2half(Wq[n * kD + 2 * kp + 1]));
        return;
    }
    id -= 32768;
    if (id < 65536) {                          // WrefT [256][256] fp32
        int k = id >> 8, n = id & 255;
        ws[WS_WREFT + id] = Wref[n * kD + k];
        return;
    }
}

// ---------------- encoder: bidir LSTM, 4 rows per block, fp16 weights ----------------
__global__ __launch_bounds__(512) void k_encoder(const float* __restrict__ inp,
                                                 float* __restrict__ ws) {
    const int dir = blockIdx.x & 1;
    const int b0  = (blockIdx.x >> 1) * 4;
    const int tid = threadIdx.x;
    const int jq  = tid & 127;                 // j-quad: j = 4*jq
    const int kg  = tid >> 7;                  // 0..3, 32 k's each
    __shared__ __align__(16) float shT[kH][4]; // h transposed [k][r]
    __shared__ float scs[4][kH];               // c state [r][k]
    __shared__ float sg[4][kG];                // gates [r][j]
    __shared__ __align__(16) float uniE[4 * 4 * 512]; // partials [kg][r][j] (32KB)
    __shared__ float sx[4][2];
    if (tid < 512) { shT[tid & 127][tid >> 7] = 0.f; scs[tid >> 7][tid & 127] = 0.f; }
    const float2* Wt = (const float2*)((const __half*)(ws + WS_EWHHH) + (size_t)dir * kH * kG); // [128][128] x half4
    const float4  cg = *(const float4*)(ws + WS_ECG + (size_t)(dir * 512 + tid) * 4); // j = tid
    float* enc = ws + WS_ENC;
    float* hst = ws + WS_HST;
    float4* uniE4 = (float4*)uniE;
    __syncthreads();
    for (int s = 0; s < kT; ++s) {
        const int t = dir ? (kT - 1 - s) : s;
        if (tid < 8) { int r = tid >> 1, c = tid & 1; sx[r][c] = inp[((size_t)(b0 + r) * kT + t) * 2 + c]; }
        {   // partial gates: thread (jq, kg): 32 k, 4 rows, 4 j (fp16 weights)
            float a0x=0,a0y=0,a0z=0,a0w=0, a1x=0,a1y=0,a1z=0,a1w=0;
            float a2x=0,a2y=0,a2z=0,a2w=0, a3x=0,a3y=0,a3z=0,a3w=0;
            #pragma unroll 8
            for (int kk = 0; kk < 32; ++kk) {
                int k = kg * 32 + kk;
                float2 wraw = Wt[k * 128 + jq];
                const __half2* hw = (const __half2*)&wraw;
                float2 wA = __half22float2(hw[0]);
                float2 wB = __half22float2(hw[1]);
                float4 x = *(const float4*)&shT[k][0];
                a0x += x.x*wA.x; a0y += x.x*wA.y; a0z += x.x*wB.x; a0w += x.x*wB.y;
                a1x += x.y*wA.x; a1y += x.y*wA.y; a1z += x.y*wB.x; a1w += x.y*wB.y;
                a2x += x.z*wA.x; a2y += x.z*wA.y; a2z += x.z*wB.x; a2w += x.z*wB.y;
                a3x += x.w*wA.x; a3y += x.w*wA.y; a3z += x.w*wB.x; a3w += x.w*wB.y;
            }
            uniE4[(kg * 4 + 0) * 128 + jq] = make_float4(a0x,a0y,a0z,a0w);
            uniE4[(kg * 4 + 1) * 128 + jq] = make_float4(a1x,a1y,a1z,a1w);
            uniE4[(kg * 4 + 2) * 128 + jq] = make_float4(a2x,a2y,a2z,a2w);
            uniE4[(kg * 4 + 3) * 128 + jq] = make_float4(a3x,a3y,a3z,a3w);
        }
        __syncthreads();
        {   // reduce + input term: j = tid
            #pragma unroll
            for (int r = 0; r < 4; ++r) {
                float g = cg.z + sx[r][0] * cg.x + sx[r][1] * cg.y;
                #pragma unroll
                for (int g4 = 0; g4 < 4; ++g4) g += uniE[(g4 * 4 + r) * 512 + tid];
                sg[r][tid] = g;
            }
        }
        __syncthreads();
        {   // cell: tid<512 -> (r, k)
            const int r = tid >> 7, k = tid & 127;
            float gi = sg[r][k], gf = sg[r][k + 128], gg = sg[r][k + 256], go = sg[r][k + 384];
            float cc = sigf(gf) * scs[r][k] + sigf(gi) * tanhf_(gg);
            float hh = sigf(go) * tanhf_(cc);
            scs[r][k] = cc; shT[k][r] = hh;
            enc[((size_t)(b0 + r) * kT + t) * kD + dir * kH + k] = hh;
            if (s == kT - 1) {
                hst[(size_t)(dir * 2 + 0) * kB * kH + (size_t)(b0 + r) * kH + k] = hh;
                hst[(size_t)(dir * 2 + 1) * kB * kH + (size_t)(b0 + r) * kH + k] = cc;
            }
        }
        __syncthreads();
    }
}

// ---------------- ref = enc @ W_ref.T, stored transposed [B][D][T] ----------------
__global__ __launch_bounds__(256) void k_refgemm(float* __restrict__ ws) {
    const int tid = threadIdx.x;
    const int m0 = blockIdx.x * 20;            // 20 bt-rows, always within one b
    const int b = m0 / kT, t0 = m0 % kT;
    __shared__ float se[20][kD];
    __shared__ float so[20][257];              // +1 pad for transposed read
    const float* enc = ws + WS_ENC;
    const float* WrT = ws + WS_WREFT;
    float* refT = ws + WS_REFT;
    #pragma unroll
    for (int i = 0; i < 20; ++i) se[i][tid] = enc[(size_t)(m0 + i) * kD + tid];
    __syncthreads();
    float acc[20];
    #pragma unroll
    for (int r = 0; r < 20; ++r) acc[r] = 0.f;
    #pragma unroll 2
    for (int k = 0; k < kD; ++k) {
        float w = WrT[k * kD + tid];
        #pragma unroll
        for (int r = 0; r < 20; ++r) acc[r] += se[r][k] * w;
    }
    #pragma unroll
    for (int r = 0; r < 20; ++r) so[r][tid] = acc[r];
    __syncthreads();
    #pragma unroll
    for (int i = 0; i < 20; ++i) {
        int idx = i * 256 + tid;
        int d = idx / 20, tt = idx - d * 20;
        refT[(size_t)b * kD * kT + d * kT + t0 + tt] = so[tt][d];
    }
}

// ---------------- process: 100-step pointer loop, 2 rows per block ----------------
__global__ __launch_bounds__(1024) void k_process(const float* __restrict__ vw,
                                                  const float* __restrict__ vb,
                                                  float* __restrict__ ws) {
    const int tid = threadIdx.x;
    const int b0 = blockIdx.x * 2;
    // xcat2[jh][k][r]: k<256 = pin (dup across jh), k>=256 = h(dir=jh)
    __shared__ __align__(16) float xcat2[2][384][2];
    __shared__ float pc[2][2][kH];             // c state [dir][r][k]
    __shared__ __align__(16) float uni[8192];  // 32KB union: gates-part / q-part / sc-part / gl-part
    __shared__ float qv[2][kD];
    __shared__ float at[2][128];
    __shared__ float vwS[kD];
    __shared__ float sbias[1024];
    const float* PB   = ws + WS_PB;
    const float* refT = ws + WS_REFT;
    const float* enc  = ws + WS_ENC;
    const float* hst  = ws + WS_HST;
    const float2* PWh4 = (const float2*)(ws + WS_PWH);      // [384][256] x half4(8B)
    const __half2* WqP = (const __half2*)(ws + WS_WQH);     // [128][256]
    // init
    if (tid < 512) {                           // states: (r, dir, k)
        int r = tid >> 8, dirk = tid & 255, dir = dirk >> 7, k = dirk & 127;
        xcat2[dir][256 + k][r] = hst[(size_t)(dir * 2 + 0) * kB * kH + (size_t)(b0 + r) * kH + k];
        pc[dir][r][k]          = hst[(size_t)(dir * 2 + 1) * kB * kH + (size_t)(b0 + r) * kH + k];
    }
    { int jh = tid >> 9, rk = tid & 511, k = rk >> 1, r = rk & 1; xcat2[jh][k][r] = 0.f; }
    if (tid < kD) vwS[tid] = vw[tid];
    sbias[tid] = PB[tid];
    const float vbias = vb[0];
    const int jq = tid & 255;                  // j-quad: j = 4*jq
    const int kg = tid >> 8;                   // 0..3, 96 k's each
    const int jh = (jq >= 128);
    float4* uni4 = (float4*)uni;
    __syncthreads();

    for (int step = 0; step < kT; ++step) {
        {   // P1 gates partial: thread (jq,kg): 96 k x 2 rows x 4 j (fp16 weights)
            float a00=0,a01=0,a02=0,a03=0, a10=0,a11=0,a12=0,a13=0;
            const float2* xk = (const float2*)&xcat2[jh][0][0];
            #pragma unroll 8
            for (int kk = 0; kk < 96; ++kk) {
                int k = kg * 96 + kk;
                float2 wraw = PWh4[(size_t)k * 256 + jq];
                const __half2* hw = (const __half2*)&wraw;
                float2 wA = __half22float2(hw[0]);
                float2 wB = __half22float2(hw[1]);
                float2 x = xk[k];
                a00 += x.x*wA.x; a01 += x.x*wA.y; a02 += x.x*wB.x; a03 += x.x*wB.y;
                a10 += x.y*wA.x; a11 += x.y*wA.y; a12 += x.y*wB.x; a13 += x.y*wB.y;
            }
            uni4[(kg * 2 + 0) * 256 + jq] = make_float4(a00,a01,a02,a03);
            uni4[(kg * 2 + 1) * 256 + jq] = make_float4(a10,a11,a12,a13);
        }
        __syncthreads();
        if (tid < 512) {                       // P3 cells with fused gate reduce: (r, dir, k)
            int r = tid >> 8, dirk = tid & 255, dir = dirk >> 7, k = dirk & 127;
            int base = dir * 512;
            int j0 = base + k, j1 = base + 128 + k, j2 = base + 256 + k, j3 = base + 384 + k;
            float gi = sbias[j0], gf = sbias[j1], gg = sbias[j2], go = sbias[j3];
            #pragma unroll
            for (int g4 = 0; g4 < 4; ++g4) {
                const float* u = &uni[(g4 * 2 + r) * 1024];
                gi += u[j0]; gf += u[j1]; gg += u[j2]; go += u[j3];
            }
            float cc = sigf(gf) * pc[dir][r][k] + sigf(gi) * tanhf_(gg);
            float hh = sigf(go) * tanhf_(cc);
            pc[dir][r][k] = cc; xcat2[dir][256 + k][r] = hh;
        }
        __syncthreads();
        if (step < kT - 1) {
            {   // P4 q partial: thread (n = tid&255, kh = tid>>8): 32 k-pairs, both rows
                int n = tid & 255, kh = tid >> 8;
                float q0 = 0.f, q1 = 0.f;
                #pragma unroll 8
                for (int i = 0; i < 32; ++i) {
                    int kp = kh * 32 + i;
                    int src = kp >> 6;               // 0 -> hf, 1 -> hb
                    int lk = (kp & 63) * 2;          // local k (even)
                    float2 wf = __half22float2(WqP[kp * 256 + n]);
                    float4 xx = *(const float4*)&xcat2[src][256 + lk][0];
                    q0 += xx.x * wf.x + xx.z * wf.y;
                    q1 += xx.y * wf.x + xx.w * wf.y;
                }
                uni[(kh * 2 + 0) * 256 + n] = q0;
                uni[(kh * 2 + 1) * 256 + n] = q1;
            }
            __syncthreads();
            if (tid < 512) {                   // P5 q reduce
                int r = tid >> 8, n = tid & 255;
                float q = 0.f;
                #pragma unroll
                for (int kh = 0; kh < 4; ++kh) q += uni[(kh * 2 + r) * 256 + n];
                qv[r][n] = q;
            }
            __syncthreads();
            if (tid < 800) {                   // P6 scores partial: (r, dg, t), 64 d each
                int r = tid / 400, rem = tid - r * 400;
                int dg = rem / 100, t = rem - dg * 100;
                const float* rrow = refT + ((size_t)(b0 + r) * kD + dg * 64) * kT + t;
                float acc = 0.f;
                #pragma unroll 8
                for (int i = 0; i < 64; ++i) {
                    int d = dg * 64 + i;
                    acc += vwS[d] * tanhf_(rrow[(size_t)i * kT] + qv[r][d]);
                }
                uni[(r * 4 + dg) * 100 + t] = acc;
            }
            __syncthreads();
            {   // P7 softmax over t: wave r (r<2)
                int wv = tid >> 6, l = tid & 63;
                if (wv < 2) {
                    int r = wv;
                    float s1 = vbias + uni[(r*4+0)*100 + l] + uni[(r*4+1)*100 + l]
                                     + uni[(r*4+2)*100 + l] + uni[(r*4+3)*100 + l];
                    float s2 = -3.0e38f;
                    if (l + 64 < kT)
                        s2 = vbias + uni[(r*4+0)*100 + l+64] + uni[(r*4+1)*100 + l+64]
                                   + uni[(r*4+2)*100 + l+64] + uni[(r*4+3)*100 + l+64];
                    float m = fmaxf(s1, s2);
                    #pragma unroll
                    for (int off = 32; off > 0; off >>= 1) m = fmaxf(m, __shfl_xor(m, off));
                    float e1 = __expf(s1 - m);
                    float e2 = (l + 64 < kT) ? __expf(s2 - m) : 0.f;
                    float ssum = e1 + e2;
                    #pragma unroll
                    for (int off = 32; off > 0; off >>= 1) ssum += __shfl_xor(ssum, off);
                    float inv = rcpf(ssum);
                    at[r][l] = e1 * inv;
                    at[r][l + 64] = e2 * inv;
                }
            }
            __syncthreads();
            {   // P8 glimpse partial: (d = tid&255, r = bit8, th = bit9): 50 t each
                int d = tid & 255, r = (tid >> 8) & 1, th = tid >> 9;
                const float* erow = enc + ((size_t)(b0 + r) * kT + th * 50) * kD + d;
                float acc = 0.f;
                #pragma unroll 10
                for (int i = 0; i < 50; ++i)
                    acc += at[r][th * 50 + i] * erow[(size_t)i * kD];
                uni[(th * 2 + r) * 256 + d] = acc;
            }
            __syncthreads();
            if (tid < 512) {                   // P9 glimpse reduce -> pin (both jh copies)
                int r = tid >> 8, d = tid & 255;
                float v = uni[(0 * 2 + r) * 256 + d] + uni[(1 * 2 + r) * 256 + d];
                xcat2[0][d][r] = v; xcat2[1][d][r] = v;
            }
            __syncthreads();
        }
    }
    // write final pout = [hf | hb]
    float* pout = ws + WS_POUT;
    if (tid < 512) {
        int r = tid >> 8, d = tid & 255;
        pout[(size_t)(b0 + r) * kD + d] = (d < 128) ? xcat2[0][256 + d][r]
                                                    : xcat2[1][256 + d - 128][r];
    }
}

// ---------------- final MLP head ----------------
__global__ __launch_bounds__(128) void k_mlp(const float* __restrict__ W1, const float* __restrict__ b1,
                                             const float* __restrict__ W2, const float* __restrict__ b2,
                                             const float* __restrict__ ws, float* __restrict__ out) {
    const int tid = threadIdx.x;
    const int b0 = blockIdx.x * 4;
    __shared__ float sp[4][kD];
    __shared__ float hid[4][kMID];
    const float* pout = ws + WS_POUT;
    #pragma unroll
    for (int i = 0; i < 8; ++i) {
        int f = i * 128 + tid;
        int r = f >> 8, k = f & 255;
        sp[r][k] = pout[(size_t)(b0 + r) * kD + k];
    }
    __syncthreads();
    if (tid < kMID) {
        int m = tid;
        #pragma unroll
        for (int r = 0; r < 4; ++r) {
            float acc = b1[m];
            for (int k = 0; k < kD; ++k) acc += sp[r][k] * W1[m * kD + k];
            hid[r][m] = fmaxf(acc, 0.f);
        }
    }
    __syncthreads();
    if (tid < 4) {
        float acc = b2[0];
        for (int m = 0; m < kMID; ++m) acc += hid[tid][m] * W2[m];
        out[b0 + tid] = acc;
    }
}

extern "C" void kernel_launch(void* const* d_in, const int* in_sizes, int n_in,
                              void* d_out, int out_size, void* d_ws, size_t ws_size,
                              hipStream_t stream) {
    (void)in_sizes; (void)n_in; (void)out_size; (void)ws_size;
    const float* inp    = (const float*)d_in[0];
    const float* Wemb   = (const float*)d_in[1];
    const float* eWih_f = (const float*)d_in[2];
    const float* eWhh_f = (const float*)d_in[3];
    const float* eb_f   = (const float*)d_in[4];
    const float* eWih_b = (const float*)d_in[5];
    const float* eWhh_b = (const float*)d_in[6];
    const float* eb_b   = (const float*)d_in[7];
    const float* Wref   = (const float*)d_in[8];
    const float* Wq     = (const float*)d_in[9];
    const float* vw     = (const float*)d_in[10];
    const float* vb     = (const float*)d_in[11];
    const float* pWih_f = (const float*)d_in[12];
    const float* pWhh_f = (const float*)d_in[13];
    const float* pb_f   = (const float*)d_in[14];
    const float* pWih_b = (const float*)d_in[15];
    const float* pWhh_b = (const float*)d_in[16];
    const float* pb_b   = (const float*)d_in[17];
    const float* W1     = (const float*)d_in[18];
    const float* b1     = (const float*)d_in[19];
    const float* W2     = (const float*)d_in[20];
    const float* b2     = (const float*)d_in[21];
    float* ws  = (float*)d_ws;
    float* out = (float*)d_out;

    k_prep_ec<<<4, 256, 0, stream>>>(eWih_f, eWih_b, eb_f, eb_b, Wemb, ws);
    k_prep_tr<<<2436, 256, 0, stream>>>(eWhh_f, eWhh_b, pWih_f, pWih_b,
                                        pWhh_f, pWhh_b, pb_f, pb_b, Wq, Wref, ws);
    k_encoder<<<256, 512, 0, stream>>>(inp, ws);
    k_refgemm<<<2560, 256, 0, stream>>>(ws);
    k_process<<<256, 1024, 0, stream>>>(vw, vb, ws);
    k_mlp<<<128, 128, 0, stream>>>(W1, b1, W2, b2, ws, out);
}

// Round 4
// 2279.868 us; speedup vs baseline: 7.2582x; 1.4497x over previous
//
#include <hip/hip_runtime.h>

// Critic_Net pointer-network forward. fp32 state/accumulate, fp16 weights +
// fp16 activations (enc/refT) + v_dot2_f32_f16 GEMM cores (R4).

constexpr int kH = 128, kE = 128, kD = 256, kB = 512, kT = 100, kG = 512, kMID = 100;

typedef _Float16 half2_t __attribute__((ext_vector_type(2)));

// ws layout (float units)
constexpr size_t WS_ENCH  = 0;                                 // half[B][T][D]   (6,553,600 f)
constexpr size_t WS_REFTH = WS_ENCH  + (size_t)kB * kT * kD/2; // half[B][D][T]
constexpr size_t WS_EW2   = WS_REFTH + (size_t)kB * kD * kT/2; // half2[2][64][512]  (65,536 f)
constexpr size_t WS_ECG   = WS_EW2   + 65536;                  // f32 [2][512][4]
constexpr size_t WS_PW2   = WS_ECG   + 4096;                   // half2[192][1024]   (196,608 f)
constexpr size_t WS_PB    = WS_PW2   + 196608;                 // f32 [1024]
constexpr size_t WS_WQ2   = WS_PB    + 1024;                   // half2[128][256]    (32,768 f)
constexpr size_t WS_WREFT = WS_WQ2   + 32768;                  // f32 [D][D]
constexpr size_t WS_HST   = WS_WREFT + (size_t)kD * kD;        // f32 [4][B][H]
constexpr size_t WS_POUT  = WS_HST   + (size_t)4 * kB * kH;    // f32 [B][D]

__device__ __forceinline__ float rcpf(float x) { return __builtin_amdgcn_rcpf(x); }
__device__ __forceinline__ float sigf(float x) { return rcpf(1.0f + __expf(-x)); }
__device__ __forceinline__ float tanhf_(float x) {
    float t = __expf(2.0f * x);            // inf-safe: rcp(inf)=0 -> 1; t->0 -> -1
    return 1.0f - 2.0f * rcpf(1.0f + t);
}
__device__ __forceinline__ float fdot2(half2_t a, half2_t b, float c) {
#if __has_builtin(__builtin_amdgcn_fdot2)
    return __builtin_amdgcn_fdot2(a, b, c, false);
#else
    return c + (float)a.x * (float)b.x + (float)a.y * (float)b.y;
#endif
}

// ---------------- prep: encoder input coefficients ----------------
__global__ void k_prep_ec(const float* __restrict__ Wih_f, const float* __restrict__ Wih_b,
                          const float* __restrict__ b_f, const float* __restrict__ b_b,
                          const float* __restrict__ Wemb, float* __restrict__ ws) {
    int id = blockIdx.x * 256 + threadIdx.x;   // 0..1023 : (dir, j)
    int dir = id >> 9, j = id & 511;
    const float* Wih = dir ? Wih_b : Wih_f;
    const float* bb  = dir ? b_b   : b_f;
    float c0 = 0.f, c1 = 0.f;
    for (int e = 0; e < kE; ++e) {
        float w = Wih[j * kE + e];
        c0 += w * Wemb[e * 2 + 0];
        c1 += w * Wemb[e * 2 + 1];
    }
    float* ecg = ws + WS_ECG + (size_t)id * 4;
    ecg[0] = c0; ecg[1] = c1; ecg[2] = bb[j]; ecg[3] = 0.f;
}

// ---------------- prep: weight transposes / k-pair half2 packing ----------------
__global__ void k_prep_tr(const float* __restrict__ eWhh_f, const float* __restrict__ eWhh_b,
                          const float* __restrict__ pWih_f, const float* __restrict__ pWih_b,
                          const float* __restrict__ pWhh_f, const float* __restrict__ pWhh_b,
                          const float* __restrict__ pb_f, const float* __restrict__ pb_b,
                          const float* __restrict__ Wq, const float* __restrict__ Wref,
                          float* __restrict__ ws) {
    int id = blockIdx.x * 256 + threadIdx.x;   // exactly 361,472 threads
    if (id < 65536) {                          // EW2 half2[2][64][512]: {W[j][2kp],W[j][2kp+1]}
        int dir = id >> 15, rem = id & 32767, kp = rem >> 9, j = rem & 511;
        const float* W = dir ? eWhh_b : eWhh_f;
        half2_t v = {(_Float16)W[j * kH + 2 * kp], (_Float16)W[j * kH + 2 * kp + 1]};
        ((half2_t*)(ws + WS_EW2))[id] = v;
        return;
    }
    id -= 65536;
    if (id < 196608) {                         // PW2 half2[192][1024]
        int kp = id >> 10, j = id & 1023;
        int k0 = 2 * kp, k1 = 2 * kp + 1;
        float a, b;
        if (k0 < 256) {
            a = (j < 512) ? pWih_f[j * kD + k0] : pWih_b[(j - 512) * kD + k0];
            b = (j < 512) ? pWih_f[j * kD + k1] : pWih_b[(j - 512) * kD + k1];
        } else {
            a = (j < 512) ? pWhh_f[j * kH + (k0 - 256)] : pWhh_b[(j - 512) * kH + (k0 - 256)];
            b = (j < 512) ? pWhh_f[j * kH + (k1 - 256)] : pWhh_b[(j - 512) * kH + (k1 - 256)];
        }
        half2_t v = {(_Float16)a, (_Float16)b};
        ((half2_t*)(ws + WS_PW2))[id] = v;
        return;
    }
    id -= 196608;
    if (id < 1024) {                           // PB [1024] fp32
        ws[WS_PB + id] = (id < 512) ? pb_f[id] : pb_b[id - 512];
        return;
    }
    id -= 1024;
    if (id < 32768) {                          // WQ2 half2[128][256]: {Wq[n][2kp],Wq[n][2kp+1]}
        int kp = id >> 8, n = id & 255;
        half2_t v = {(_Float16)Wq[n * kD + 2 * kp], (_Float16)Wq[n * kD + 2 * kp + 1]};
        ((half2_t*)(ws + WS_WQ2))[id] = v;
        return;
    }
    id -= 32768;
    if (id < 65536) {                          // WrefT [256][256] fp32
        int k = id >> 8, n = id & 255;
        ws[WS_WREFT + id] = Wref[n * kD + k];
        return;
    }
}

// ---------------- encoder: bidir LSTM, 4 rows per block, fdot2 ----------------
__global__ __launch_bounds__(512) void k_encoder(const float* __restrict__ inp,
                                                 float* __restrict__ ws) {
    const int dir = blockIdx.x & 1;
    const int b0  = (blockIdx.x >> 1) * 4;
    const int tid = threadIdx.x;
    const int jq  = tid & 127;                 // j4 = 4*jq
    const int kg  = tid >> 7;                  // 0..3, 16 kp each
    __shared__ __align__(16) half2_t shT2[64][4];       // h pairs [kp][r] (1KB)
    __shared__ float scs[4][kH];                        // c state
    __shared__ __align__(16) float uniE[4 * 4 * 512];   // partials [kg][r][j] (32KB)
    __shared__ __align__(16) float4 secg[512];          // input coeffs per j (8KB)
    __shared__ float sx[4][2];
    if (tid < 256) ((float*)shT2)[tid] = 0.f;
    if (tid < 512) scs[tid >> 7][tid & 127] = 0.f;
    secg[tid] = *(const float4*)(ws + WS_ECG + (size_t)(dir * 512 + tid) * 4);
    const float4* EW2f4 = (const float4*)(ws + WS_EW2) + (size_t)dir * 64 * 128; // [64][128]
    _Float16* ench = (_Float16*)(ws + WS_ENCH);
    float* hst = ws + WS_HST;
    float4* uniE4 = (float4*)uniE;
    __syncthreads();
    for (int s = 0; s < kT; ++s) {
        const int t = dir ? (kT - 1 - s) : s;
        if (tid < 8) { int r = tid >> 1, c = tid & 1; sx[r][c] = inp[((size_t)(b0 + r) * kT + t) * 2 + c]; }
        {   // partial gates: (jq, kg): 16 kp, 4 rows, 4 j
            float aa[16];
            #pragma unroll
            for (int i = 0; i < 16; ++i) aa[i] = 0.f;
            #pragma unroll 8
            for (int kk = 0; kk < 16; ++kk) {
                int kp = kg * 16 + kk;
                float4 wraw = EW2f4[kp * 128 + jq];
                float4 xraw = *(const float4*)&shT2[kp][0];
                const half2_t* wp = (const half2_t*)&wraw;
                const half2_t* xp = (const half2_t*)&xraw;
                #pragma unroll
                for (int j = 0; j < 4; ++j)
                    #pragma unroll
                    for (int r = 0; r < 4; ++r)
                        aa[j * 4 + r] = fdot2(wp[j], xp[r], aa[j * 4 + r]);
            }
            #pragma unroll
            for (int r = 0; r < 4; ++r)
                uniE4[(kg * 4 + r) * 128 + jq] = make_float4(aa[0*4+r], aa[1*4+r], aa[2*4+r], aa[3*4+r]);
        }
        __syncthreads();
        {   // cell with fused reduce: (r, k)
            const int r = tid >> 7, k = tid & 127;
            float4 c0 = secg[k], c1 = secg[128 + k], c2 = secg[256 + k], c3 = secg[384 + k];
            float x0 = sx[r][0], x1 = sx[r][1];
            float gi = c0.z + x0 * c0.x + x1 * c0.y;
            float gf = c1.z + x0 * c1.x + x1 * c1.y;
            float gg = c2.z + x0 * c2.x + x1 * c2.y;
            float go = c3.z + x0 * c3.x + x1 * c3.y;
            #pragma unroll
            for (int g4 = 0; g4 < 4; ++g4) {
                const float* u = &uniE[(g4 * 4 + r) * 512];
                gi += u[k]; gf += u[k + 128]; gg += u[k + 256]; go += u[k + 384];
            }
            float cc = sigf(gf) * scs[r][k] + sigf(gi) * tanhf_(gg);
            float hh = sigf(go) * tanhf_(cc);
            scs[r][k] = cc;
            ((_Float16*)shT2)[((k >> 1) * 4 + r) * 2 + (k & 1)] = (_Float16)hh;
            ench[((size_t)(b0 + r) * kT + t) * kD + dir * kH + k] = (_Float16)hh;
            if (s == kT - 1) {
                hst[(size_t)(dir * 2 + 0) * kB * kH + (size_t)(b0 + r) * kH + k] = hh;
                hst[(size_t)(dir * 2 + 1) * kB * kH + (size_t)(b0 + r) * kH + k] = cc;
            }
        }
        __syncthreads();
    }
}

// ---------------- ref = enc @ W_ref.T -> refTh fp16 [B][D][T] ----------------
__global__ __launch_bounds__(256) void k_refgemm(float* __restrict__ ws) {
    const int tid = threadIdx.x;
    const int m0 = blockIdx.x * 20;            // 20 bt-rows, within one b
    const int b = m0 / kT, t0 = m0 % kT;
    __shared__ float se[20][kD];
    __shared__ float so[20][257];
    const _Float16* ench = (const _Float16*)(ws + WS_ENCH);
    const float* WrT = ws + WS_WREFT;
    _Float16* refTh = (_Float16*)(ws + WS_REFTH);
    #pragma unroll
    for (int i = 0; i < 20; ++i) se[i][tid] = (float)ench[(size_t)(m0 + i) * kD + tid];
    __syncthreads();
    float acc[20];
    #pragma unroll
    for (int r = 0; r < 20; ++r) acc[r] = 0.f;
    #pragma unroll 2
    for (int k = 0; k < kD; ++k) {
        float w = WrT[k * kD + tid];
        #pragma unroll
        for (int r = 0; r < 20; ++r) acc[r] += se[r][k] * w;
    }
    #pragma unroll
    for (int r = 0; r < 20; ++r) so[r][tid] = acc[r];
    __syncthreads();
    #pragma unroll
    for (int i = 0; i < 20; ++i) {
        int idx = i * 256 + tid;
        int d = idx / 20, tt = idx - d * 20;
        refTh[(size_t)b * kD * kT + d * kT + t0 + tt] = (_Float16)so[tt][d];
    }
}

// ---------------- process: 100-step pointer loop, 2 rows per block ----------------
__global__ __launch_bounds__(1024) void k_process(const float* __restrict__ vw,
                                                  const float* __restrict__ vb,
                                                  float* __restrict__ ws) {
    const int tid = threadIdx.x;
    const int b0 = blockIdx.x * 2;
    // xh2[jh][kp][r]: kp<128 = pin pairs (dup across jh); kp in [128,192) = h(dir=jh) pairs
    __shared__ __align__(16) half2_t xh2[2][192][2];    // 3KB
    __shared__ float pc[2][2][kH];                      // c state [dir][r][k]
    __shared__ float hfp[2][2][kH];                     // h fp32 [dir][r][k]
    __shared__ __align__(16) float uni[8192];           // 32KB scratch
    __shared__ float qv[2][kD];
    __shared__ float at[2][128];
    __shared__ float vwS[kD];
    __shared__ float sbias[1024];
    const float* PB   = ws + WS_PB;
    const _Float16* refTh = (const _Float16*)(ws + WS_REFTH);
    const _Float16* ench  = (const _Float16*)(ws + WS_ENCH);
    const float* hst  = ws + WS_HST;
    const float4* PW2f4 = (const float4*)(ws + WS_PW2); // [192][256] float4
    const float*  WQ2f  = ws + WS_WQ2;                  // [128][256] half2-as-float
    _Float16* xf = (_Float16*)xh2;
    // init
    if (tid < 512) {                           // zero pin region: (jh, kp<128, r)
        int zjh = tid >> 8, zkp = (tid >> 1) & 127, zr = tid & 1;
        ((float*)xh2)[(zjh * 192 + zkp) * 2 + zr] = 0.f;
    }
    if (tid < 512) {                           // states: (r, dir, k)
        int r = tid >> 8, dirk = tid & 255, dir = dirk >> 7, k = dirk & 127;
        float hv = hst[(size_t)(dir * 2 + 0) * kB * kH + (size_t)(b0 + r) * kH + k];
        pc[dir][r][k]  = hst[(size_t)(dir * 2 + 1) * kB * kH + (size_t)(b0 + r) * kH + k];
        hfp[dir][r][k] = hv;
        xf[((dir * 192 + 128 + (k >> 1)) * 2 + r) * 2 + (k & 1)] = (_Float16)hv;
    }
    if (tid < kD) vwS[tid] = vw[tid];
    sbias[tid] = PB[tid];
    const float vbias = vb[0];
    const int jq = tid & 255;                  // j4 = 4*jq
    const int kg = tid >> 8;                   // 0..3, 48 kp each
    const int jh = (jq >= 128);
    float4* uni4 = (float4*)uni;
    __syncthreads();

    for (int step = 0; step < kT; ++step) {
        {   // P1 gates partial: (jq, kg): 48 kp x 2 rows x 4 j, fdot2
            float a00=0,a01=0,a02=0,a03=0, a10=0,a11=0,a12=0,a13=0;
            #pragma unroll 8
            for (int kk = 0; kk < 48; ++kk) {
                int kp = kg * 48 + kk;
                float4 wraw = PW2f4[(size_t)kp * 256 + jq];
                float2 xraw = *(const float2*)&xh2[jh][kp][0];
                const half2_t* wp = (const half2_t*)&wraw;
                const half2_t* xp = (const half2_t*)&xraw;
                a00 = fdot2(wp[0], xp[0], a00); a01 = fdot2(wp[1], xp[0], a01);
                a02 = fdot2(wp[2], xp[0], a02); a03 = fdot2(wp[3], xp[0], a03);
                a10 = fdot2(wp[0], xp[1], a10); a11 = fdot2(wp[1], xp[1], a11);
                a12 = fdot2(wp[2], xp[1], a12); a13 = fdot2(wp[3], xp[1], a13);
            }
            uni4[(kg * 2 + 0) * 256 + jq] = make_float4(a00,a01,a02,a03);
            uni4[(kg * 2 + 1) * 256 + jq] = make_float4(a10,a11,a12,a13);
        }
        __syncthreads();
        if (tid < 512) {                       // P2 cells with fused reduce: (r, dir, k)
            int r = tid >> 8, dirk = tid & 255, dir = dirk >> 7, k = dirk & 127;
            int base = dir * 512;
            int j0 = base + k, j1 = base + 128 + k, j2 = base + 256 + k, j3 = base + 384 + k;
            float gi = sbias[j0], gf = sbias[j1], gg = sbias[j2], go = sbias[j3];
            #pragma unroll
            for (int g4 = 0; g4 < 4; ++g4) {
                const float* u = &uni[(g4 * 2 + r) * 1024];
                gi += u[j0]; gf += u[j1]; gg += u[j2]; go += u[j3];
            }
            float cc = sigf(gf) * pc[dir][r][k] + sigf(gi) * tanhf_(gg);
            float hh = sigf(go) * tanhf_(cc);
            pc[dir][r][k] = cc; hfp[dir][r][k] = hh;
            xf[((dir * 192 + 128 + (k >> 1)) * 2 + r) * 2 + (k & 1)] = (_Float16)hh;
        }
        __syncthreads();
        if (step < kT - 1) {
            {   // P4 q partial: (n = tid&255, kh = tid>>8): 32 kp, both rows, fdot2
                int n = tid & 255, kh = tid >> 8;
                float q0 = 0.f, q1 = 0.f;
                #pragma unroll 8
                for (int i = 0; i < 32; ++i) {
                    int kp = kh * 32 + i;
                    int dir = kp >> 6, lkp = kp & 63;
                    float wr = WQ2f[kp * 256 + n];
                    float2 xraw = *(const float2*)&xh2[dir][128 + lkp][0];
                    const half2_t* xp = (const half2_t*)&xraw;
                    half2_t w = *(const half2_t*)&wr;
                    q0 = fdot2(w, xp[0], q0);
                    q1 = fdot2(w, xp[1], q1);
                }
                uni[(kh * 2 + 0) * 256 + n] = q0;
                uni[(kh * 2 + 1) * 256 + n] = q1;
            }
            __syncthreads();
            if (tid < 512) {                   // P5 q reduce
                int r = tid >> 8, n = tid & 255;
                float q = 0.f;
                #pragma unroll
                for (int kh = 0; kh < 4; ++kh) q += uni[(kh * 2 + r) * 256 + n];
                qv[r][n] = q;
            }
            __syncthreads();
            if (tid < 800) {                   // P6 scores partial: (r, dg, t), 64 d each
                int r = tid / 400, rem = tid - r * 400;
                int dg = rem / 100, t = rem - dg * 100;
                const _Float16* rrow = refTh + ((size_t)(b0 + r) * kD + dg * 64) * kT + t;
                float acc = 0.f;
                #pragma unroll 8
                for (int i = 0; i < 64; ++i) {
                    int d = dg * 64 + i;
                    float rv = (float)rrow[(size_t)i * kT];
                    acc += vwS[d] * tanhf_(rv + qv[r][d]);
                }
                uni[(r * 4 + dg) * 100 + t] = acc;
            }
            __syncthreads();
            {   // P7 softmax over t: wave r (r<2)
                int wv = tid >> 6, l = tid & 63;
                if (wv < 2) {
                    int r = wv;
                    float s1 = vbias + uni[(r*4+0)*100 + l] + uni[(r*4+1)*100 + l]
                                     + uni[(r*4+2)*100 + l] + uni[(r*4+3)*100 + l];
                    float s2 = -3.0e38f;
                    if (l + 64 < kT)
                        s2 = vbias + uni[(r*4+0)*100 + l+64] + uni[(r*4+1)*100 + l+64]
                                   + uni[(r*4+2)*100 + l+64] + uni[(r*4+3)*100 + l+64];
                    float m = fmaxf(s1, s2);
                    #pragma unroll
                    for (int off = 32; off > 0; off >>= 1) m = fmaxf(m, __shfl_xor(m, off));
                    float e1 = __expf(s1 - m);
                    float e2 = (l + 64 < kT) ? __expf(s2 - m) : 0.f;
                    float ssum = e1 + e2;
                    #pragma unroll
                    for (int off = 32; off > 0; off >>= 1) ssum += __shfl_xor(ssum, off);
                    float inv = rcpf(ssum);
                    at[r][l] = e1 * inv;
                    at[r][l + 64] = e2 * inv;
                }
            }
            __syncthreads();
            {   // P8 glimpse partial: (dp = tid&127 -> 2 d, r = bit7, th = tid>>8): 25 t each
                int dp = tid & 127, r = (tid >> 7) & 1, th = tid >> 8;
                const half2_t* erow = (const half2_t*)(ench + ((size_t)(b0 + r) * kT + th * 25) * kD) + dp;
                float a0 = 0.f, a1 = 0.f;
                #pragma unroll 5
                for (int i = 0; i < 25; ++i) {
                    half2_t e = erow[(size_t)i * (kD / 2)];
                    float w = at[r][th * 25 + i];
                    a0 += w * (float)e.x;
                    a1 += w * (float)e.y;
                }
                uni[(th * 2 + r) * 256 + 2 * dp]     = a0;
                uni[(th * 2 + r) * 256 + 2 * dp + 1] = a1;
            }
            __syncthreads();
            if (tid < 512) {                   // P9 glimpse reduce -> pin fp16 (both jh copies)
                int r = tid >> 8, d = tid & 255;
                float v = 0.f;
                #pragma unroll
                for (int th = 0; th < 4; ++th) v += uni[(th * 2 + r) * 256 + d];
                _Float16 hv = (_Float16)v;
                xf[((0 * 192 + (d >> 1)) * 2 + r) * 2 + (d & 1)] = hv;
                xf[((1 * 192 + (d >> 1)) * 2 + r) * 2 + (d & 1)] = hv;
            }
            __syncthreads();
        }
    }
    // write final pout = [hf | hb] (fp32 state)
    float* pout = ws + WS_POUT;
    if (tid < 512) {
        int r = tid >> 8, d = tid & 255;
        pout[(size_t)(b0 + r) * kD + d] = (d < 128) ? hfp[0][r][d] : hfp[1][r][d - 128];
    }
}

// ---------------- final MLP head ----------------
__global__ __launch_bounds__(128) void k_mlp(const float* __restrict__ W1, const float* __restrict__ b1,
                                             const float* __restrict__ W2, const float* __restrict__ b2,
                                             const float* __restrict__ ws, float* __restrict__ out) {
    const int tid = threadIdx.x;
    const int b0 = blockIdx.x * 4;
    __shared__ float sp[4][kD];
    __shared__ float hid[4][kMID];
    const float* pout = ws + WS_POUT;
    #pragma unroll
    for (int i = 0; i < 8; ++i) {
        int f = i * 128 + tid;
        int r = f >> 8, k = f & 255;
        sp[r][k] = pout[(size_t)(b0 + r) * kD + k];
    }
    __syncthreads();
    if (tid < kMID) {
        int m = tid;
        #pragma unroll
        for (int r = 0; r < 4; ++r) {
            float acc = b1[m];
            for (int k = 0; k < kD; ++k) acc += sp[r][k] * W1[m * kD + k];
            hid[r][m] = fmaxf(acc, 0.f);
        }
    }
    __syncthreads();
    if (tid < 4) {
        float acc = b2[0];
        for (int m = 0; m < kMID; ++m) acc += hid[tid][m] * W2[m];
        out[b0 + tid] = acc;
    }
}

extern "C" void kernel_launch(void* const* d_in, const int* in_sizes, int n_in,
                              void* d_out, int out_size, void* d_ws, size_t ws_size,
                              hipStream_t stream) {
    (void)in_sizes; (void)n_in; (void)out_size; (void)ws_size;
    const float* inp    = (const float*)d_in[0];
    const float* Wemb   = (const float*)d_in[1];
    const float* eWih_f = (const float*)d_in[2];
    const float* eWhh_f = (const float*)d_in[3];
    const float* eb_f   = (const float*)d_in[4];
    const float* eWih_b = (const float*)d_in[5];
    const float* eWhh_b = (const float*)d_in[6];
    const float* eb_b   = (const float*)d_in[7];
    const float* Wref   = (const float*)d_in[8];
    const float* Wq     = (const float*)d_in[9];
    const float* vw     = (const float*)d_in[10];
    const float* vb     = (const float*)d_in[11];
    const float* pWih_f = (const float*)d_in[12];
    const float* pWhh_f = (const float*)d_in[13];
    const float* pb_f   = (const float*)d_in[14];
    const float* pWih_b = (const float*)d_in[15];
    const float* pWhh_b = (const float*)d_in[16];
    const float* pb_b   = (const float*)d_in[17];
    const float* W1     = (const float*)d_in[18];
    const float* b1     = (const float*)d_in[19];
    const float* W2     = (const float*)d_in[20];
    const float* b2     = (const float*)d_in[21];
    float* ws  = (float*)d_ws;
    float* out = (float*)d_out;

    k_prep_ec<<<4, 256, 0, stream>>>(eWih_f, eWih_b, eb_f, eb_b, Wemb, ws);
    k_prep_tr<<<1412, 256, 0, stream>>>(eWhh_f, eWhh_b, pWih_f, pWih_b,
                                        pWhh_f, pWhh_b, pb_f, pb_b, Wq, Wref, ws);
    k_encoder<<<256, 512, 0, stream>>>(inp, ws);
    k_refgemm<<<2560, 256, 0, stream>>>(ws);
    k_process<<<256, 1024, 0, stream>>>(vw, vb, ws);
    k_mlp<<<128, 128, 0, stream>>>(W1, b1, W2, b2, ws, out);
}